// Round 1
// baseline (2910.126 us; speedup 1.0000x reference)
//
#include <hip/hip_runtime.h>

#define DIMV 64
#define CH 64
#define EPSB 1e-3f
#define TZ 16

__global__ void mlp_kernel(const float* __restrict__ x, const float* __restrict__ W,
                           const float* __restrict__ b, const float* __restrict__ g,
                           const float* __restrict__ be, const float* __restrict__ m,
                           const float* __restrict__ v, float* __restrict__ out, int n_total) {
    int tid = blockIdx.x * blockDim.x + threadIdx.x;
    if (tid >= n_total) return;
    int n = tid >> 6, co = tid & 63;
    const float* xr = x + n * CH;
    float acc = b[co];
#pragma unroll 8
    for (int ci = 0; ci < CH; ++ci) acc = fmaf(xr[ci], W[ci * CH + co], acc);
    acc = fmaxf(acc, 0.f);
    float scale = g[co] * rsqrtf(v[co] + EPSB);
    out[tid] = (acc - m[co]) * scale + be[co];
}

__global__ void scatter_kernel(const float* __restrict__ x, const int* __restrict__ idx,
                               float* __restrict__ grid, int n_total) {
    int tid = blockIdx.x * blockDim.x + threadIdx.x;
    if (tid >= n_total) return;
    int n = tid >> 6, c = tid & 63;
    int ix = idx[n * 3 + 0], iy = idx[n * 3 + 1], iz = idx[n * 3 + 2];
    atomicAdd(&grid[(((ix * DIMV) + iy) * DIMV + iz) * CH + c], x[tid]);
}

template <bool FUSE_INV>
__global__ __launch_bounds__(256) void conv_kernel(
    const float* __restrict__ in, const float* __restrict__ K,
    const float* __restrict__ cb, const float* __restrict__ g,
    const float* __restrict__ be, const float* __restrict__ m,
    const float* __restrict__ v, const float* __restrict__ inv,
    float* __restrict__ out) {
    // LDS slab: [dx*3+dy][z-1 .. z+16][ci]
    __shared__ float lds[9][TZ + 2][CH];   // 41472 B
    const int bx = blockIdx.x, by = blockIdx.y, z0 = blockIdx.z * TZ;
    const int tid = threadIdx.x;

    for (int e = tid; e < 9 * (TZ + 2) * CH; e += 256) {
        int ci = e & 63;
        int zi = (e >> 6) % (TZ + 2);
        int dxy = e / ((TZ + 2) * CH);
        int xx = bx + dxy / 3 - 1;
        int yy = by + dxy % 3 - 1;
        int zz = z0 + zi - 1;
        float val = 0.f;
        if (xx >= 0 && xx < DIMV && yy >= 0 && yy < DIMV && zz >= 0 && zz < DIMV) {
            int vidx = ((xx * DIMV) + yy) * DIMV + zz;
            val = in[vidx * CH + ci];
            if (FUSE_INV) val *= inv[vidx];
        }
        ((float*)lds)[e] = val;
    }
    __syncthreads();

    const int co = tid & 63;
    const int zg = tid >> 6;        // 0..3
    const int zbase = zg * 4;       // output z-offsets zbase..zbase+3 within tile
    float acc0 = 0.f, acc1 = 0.f, acc2 = 0.f, acc3 = 0.f;

    for (int dxy = 0; dxy < 9; ++dxy) {
        const float* kt = K + dxy * 3 * CH * CH;   // [dz][ci][co]
        const float* l = &lds[dxy][zbase][0];
#pragma unroll 4
        for (int ci = 0; ci < CH; ++ci) {
            float w0 = kt[ci * CH + co];
            float w1 = kt[CH * CH + ci * CH + co];
            float w2 = kt[2 * CH * CH + ci * CH + co];
            float v0 = l[0 * CH + ci];
            float v1 = l[1 * CH + ci];
            float v2 = l[2 * CH + ci];
            float v3 = l[3 * CH + ci];
            float v4 = l[4 * CH + ci];
            float v5 = l[5 * CH + ci];
            acc0 = fmaf(v0, w0, acc0); acc0 = fmaf(v1, w1, acc0); acc0 = fmaf(v2, w2, acc0);
            acc1 = fmaf(v1, w0, acc1); acc1 = fmaf(v2, w1, acc1); acc1 = fmaf(v3, w2, acc1);
            acc2 = fmaf(v2, w0, acc2); acc2 = fmaf(v3, w1, acc2); acc2 = fmaf(v4, w2, acc2);
            acc3 = fmaf(v3, w0, acc3); acc3 = fmaf(v4, w1, acc3); acc3 = fmaf(v5, w2, acc3);
        }
    }

    float scale = g[co] * rsqrtf(v[co] + EPSB);
    float sh = be[co] - m[co] * scale;
    float bias = cb[co];
    float accs[4] = {acc0, acc1, acc2, acc3};
#pragma unroll
    for (int j = 0; j < 4; ++j) {
        float r = fmaxf(accs[j] + bias, 0.f);
        out[(((bx * DIMV) + by) * DIMV + z0 + zbase + j) * CH + co] = r * scale + sh;
    }
}

__global__ void gather_kernel(const float* __restrict__ grid, const float* __restrict__ pts,
                              float* __restrict__ out, int n_total) {
    int tid = blockIdx.x * blockDim.x + threadIdx.x;
    if (tid >= n_total) return;
    int n = tid >> 6, c = tid & 63;
    float px = fminf(fmaxf(pts[n * 3 + 0], 0.f), (float)(DIMV - 1));
    float py = fminf(fmaxf(pts[n * 3 + 1], 0.f), (float)(DIMV - 1));
    float pz = fminf(fmaxf(pts[n * 3 + 2], 0.f), (float)(DIMV - 1));
    float fx = floorf(px), fy = floorf(py), fz = floorf(pz);
    float tx = px - fx, ty = py - fy, tz = pz - fz;
    int x0 = (int)fx, y0 = (int)fy, z0 = (int)fz;
    int x1 = min(x0 + 1, DIMV - 1), y1 = min(y0 + 1, DIMV - 1), z1 = min(z0 + 1, DIMV - 1);
    float wx0 = 1.f - tx, wy0 = 1.f - ty, wz0 = 1.f - tz;

    float acc = 0.f;
    acc = fmaf(wx0 * wy0 * wz0, grid[(((x0 * DIMV) + y0) * DIMV + z0) * CH + c], acc);
    acc = fmaf(wx0 * wy0 * tz,  grid[(((x0 * DIMV) + y0) * DIMV + z1) * CH + c], acc);
    acc = fmaf(wx0 * ty * wz0,  grid[(((x0 * DIMV) + y1) * DIMV + z0) * CH + c], acc);
    acc = fmaf(wx0 * ty * tz,   grid[(((x0 * DIMV) + y1) * DIMV + z1) * CH + c], acc);
    acc = fmaf(tx * wy0 * wz0,  grid[(((x1 * DIMV) + y0) * DIMV + z0) * CH + c], acc);
    acc = fmaf(tx * wy0 * tz,   grid[(((x1 * DIMV) + y0) * DIMV + z1) * CH + c], acc);
    acc = fmaf(tx * ty * wz0,   grid[(((x1 * DIMV) + y1) * DIMV + z0) * CH + c], acc);
    acc = fmaf(tx * ty * tz,    grid[(((x1 * DIMV) + y1) * DIMV + z1) * CH + c], acc);
    out[tid] += acc;
}

extern "C" void kernel_launch(void* const* d_in, const int* in_sizes, int n_in,
                              void* d_out, int out_size, void* d_ws, size_t ws_size,
                              hipStream_t stream) {
    const float* inputs = (const float*)d_in[0];
    const float* pt_coords = (const float*)d_in[1];
    const int* voxel_indexes = (const int*)d_in[2];
    const float* ppvi = (const float*)d_in[3];
    const float* w_mlp = (const float*)d_in[4];
    const float* b_mlp = (const float*)d_in[5];
    const float* g0 = (const float*)d_in[6];
    const float* be0 = (const float*)d_in[7];
    const float* m0 = (const float*)d_in[8];
    const float* v0 = (const float*)d_in[9];
    const float* k1 = (const float*)d_in[10];
    const float* cb1 = (const float*)d_in[11];
    const float* g1 = (const float*)d_in[12];
    const float* be1 = (const float*)d_in[13];
    const float* m1 = (const float*)d_in[14];
    const float* v1 = (const float*)d_in[15];
    const float* k2 = (const float*)d_in[16];
    const float* cb2 = (const float*)d_in[17];
    const float* g2 = (const float*)d_in[18];
    const float* be2 = (const float*)d_in[19];
    const float* m2 = (const float*)d_in[20];
    const float* v2 = (const float*)d_in[21];
    float* out = (float*)d_out;

    const size_t grid_elems = (size_t)DIMV * DIMV * DIMV * CH;  // 16.78M floats
    float* A = (float*)d_ws;
    float* B = A + grid_elems;

    const int n_total = in_sizes[0];           // N * C
    const int nblk = (n_total + 255) / 256;

    hipMemsetAsync(A, 0, grid_elems * sizeof(float), stream);

    mlp_kernel<<<nblk, 256, 0, stream>>>(inputs, w_mlp, b_mlp, g0, be0, m0, v0, out, n_total);
    scatter_kernel<<<nblk, 256, 0, stream>>>(inputs, voxel_indexes, A, n_total);

    dim3 cgrid(DIMV, DIMV, DIMV / TZ);
    conv_kernel<true><<<cgrid, 256, 0, stream>>>(A, k1, cb1, g1, be1, m1, v1, ppvi, B);
    conv_kernel<false><<<cgrid, 256, 0, stream>>>(B, k2, cb2, g2, be2, m2, v2, nullptr, A);

    gather_kernel<<<nblk, 256, 0, stream>>>(A, pt_coords, out, n_total);
}

// Round 2
// 548.693 us; speedup vs baseline: 5.3037x; 5.3037x over previous
//
#include <hip/hip_runtime.h>
#include <hip/hip_bf16.h>

#define DIMV 64
#define CH 64
#define EPSB 1e-3f

typedef unsigned short ushort_t;
using bf16x8 = __attribute__((ext_vector_type(8))) short;
using f32x16 = __attribute__((ext_vector_type(16))) float;

__device__ __forceinline__ unsigned short f2bf(float f) {
    union { float f; unsigned u; } x; x.f = f;
    unsigned r = x.u + 0x7fff + ((x.u >> 16) & 1);   // round-to-nearest-even
    return (unsigned short)(r >> 16);
}

__device__ __forceinline__ void store_out(unsigned short* p, float v) { *p = f2bf(v); }
__device__ __forceinline__ void store_out(float* p, float v) { *p = v; }

// ---------------- point branch ----------------
__global__ void mlp_kernel(const float* __restrict__ x, const float* __restrict__ W,
                           const float* __restrict__ b, const float* __restrict__ g,
                           const float* __restrict__ be, const float* __restrict__ m,
                           const float* __restrict__ v, float* __restrict__ out, int n_total) {
    int tid = blockIdx.x * blockDim.x + threadIdx.x;
    if (tid >= n_total) return;
    int n = tid >> 6, co = tid & 63;
    const float* xr = x + (size_t)n * CH;
    float acc = b[co];
#pragma unroll 8
    for (int ci = 0; ci < CH; ++ci) acc = fmaf(xr[ci], W[ci * CH + co], acc);
    acc = fmaxf(acc, 0.f);
    float scale = g[co] * rsqrtf(v[co] + EPSB);
    out[tid] = (acc - m[co]) * scale + be[co];
}

__global__ void scatter_kernel(const float* __restrict__ x, const int* __restrict__ idx,
                               float* __restrict__ grid, int n_total) {
    int tid = blockIdx.x * blockDim.x + threadIdx.x;
    if (tid >= n_total) return;
    int n = tid >> 6, c = tid & 63;
    int ix = idx[n * 3 + 0], iy = idx[n * 3 + 1], iz = idx[n * 3 + 2];
    atomicAdd(&grid[(size_t)(((ix * DIMV) + iy) * DIMV + iz) * CH + c], x[tid]);
}

// ---------------- pack: fp32 grid * inv -> bf16 grid ----------------
__global__ void pack_kernel(const float* __restrict__ A, const float* __restrict__ inv,
                            unsigned short* __restrict__ G1) {
    int t = blockIdx.x * 256 + threadIdx.x;          // one 16B chunk (8 ch) per thread
    if (t >= (DIMV * DIMV * DIMV * CH) / 8) return;
    int v = t >> 3, c8 = (t & 7) * 8;
    const float* src = A + (size_t)v * CH + c8;
    float s = inv[v];
    __align__(16) unsigned short tmp[8];
#pragma unroll
    for (int j = 0; j < 8; ++j) tmp[j] = f2bf(src[j] * s);
    *(int4*)(G1 + (size_t)t * 8) = *(const int4*)tmp;
}

// ---------------- weight repack into MFMA B-fragment layout ----------------
// wbuf[d][kkl][nt][lane][j] = bf16( K[d*64 + kkl*16 + (lane>>5)*8 + j][nt*32 + (lane&31)] )
__global__ void wprep_kernel(const float* __restrict__ K, unsigned short* __restrict__ wbuf) {
    int t = blockIdx.x * 256 + threadIdx.x;
    if (t >= 27 * 4 * 2 * 64 * 8) return;
    int j = t & 7;
    int l = (t >> 3) & 63;
    int nt = (t >> 9) & 1;
    int kkl = (t >> 10) & 3;
    int d = t >> 12;
    int ci = kkl * 16 + (l >> 5) * 8 + j;
    int co = nt * 32 + (l & 31);
    wbuf[t] = f2bf(K[((size_t)d * 64 + ci) * 64 + co]);
}

// ---------------- MFMA conv: C-tile 128x64 per block (2x2 xy cols x 32 z) ----------------
template <typename OutT>
__global__ __launch_bounds__(128) void conv_mfma(
    const unsigned short* __restrict__ G, const unsigned short* __restrict__ wbuf,
    const float* __restrict__ cb, const float* __restrict__ g,
    const float* __restrict__ be, const float* __restrict__ m,
    const float* __restrict__ v, OutT* __restrict__ out) {
    __shared__ __align__(16) unsigned short slab[4 * 4 * 34 * 64];  // 69632 B, swizzled
    __shared__ __align__(16) unsigned short bsm[4096];              // 8192 B
    const int tid = threadIdx.x;
    const int lane = tid & 63;
    const int w = tid >> 6;         // wave 0/1 -> x column
    const int lz = lane & 31;
    const int kg = lane >> 5;       // k-half
    const int BX = blockIdx.x, BY = blockIdx.y, BZ = blockIdx.z;
    const int x0 = 2 * BX - 1, y0 = 2 * BY - 1, z0 = 32 * BZ - 1;

    // Stage A slab once: 4352 chunks of 16B. LDS slot s at row r holds global
    // ci-chunk (s ^ (zloc&7)) so frag reads at (c ^ (zloc&7)) are conflict-spread.
    for (int it = 0; it < 34; ++it) {
        int idx = it * 128 + tid;
        int s = idx & 7;
        int r = idx >> 3;
        int zloc = r % 34;
        int ryx = r / 34;
        int yy = y0 + (ryx & 3);
        int xx = x0 + (ryx >> 2);
        int zz = z0 + zloc;
        int cg = s ^ (zloc & 7);
        int4 val = make_int4(0, 0, 0, 0);
        if ((unsigned)xx < DIMV && (unsigned)yy < DIMV && (unsigned)zz < DIMV)
            val = *(const int4*)(G + ((size_t)(((xx * DIMV) + yy) * DIMV + zz) * CH + cg * 8));
        *(int4*)(slab + r * 64 + s * 8) = val;
    }

    f32x16 acc[2][2];
#pragma unroll
    for (int mt = 0; mt < 2; ++mt)
#pragma unroll
        for (int nt = 0; nt < 2; ++nt)
#pragma unroll
            for (int r = 0; r < 16; ++r) acc[mt][nt][r] = 0.f;

    for (int d = 0; d < 27; ++d) {
        __syncthreads();                         // also covers slab staging on d=0
        const int4* wsrc = (const int4*)(wbuf + (size_t)d * 4096);
#pragma unroll
        for (int i = 0; i < 4; ++i) ((int4*)bsm)[i * 128 + tid] = wsrc[i * 128 + tid];
        __syncthreads();

        const int dx = d / 9, dy = (d / 3) % 3, dz = d % 3;
        const int zloc = lz + dz;
        const int swz = zloc & 7;
        const int rb0 = (((w + dx) * 4 + dy) * 34 + zloc) * 64;   // mt=0 row base (ushorts)

#pragma unroll
        for (int kkl = 0; kkl < 4; ++kkl) {
            const int coff = ((kkl * 2 + kg) ^ swz) * 8;
            bf16x8 a0 = *(const bf16x8*)(slab + rb0 + coff);
            bf16x8 a1 = *(const bf16x8*)(slab + rb0 + 34 * 64 + coff);
            bf16x8 b0 = *(const bf16x8*)(bsm + kkl * 1024 + lane * 8);
            bf16x8 b1 = *(const bf16x8*)(bsm + kkl * 1024 + 512 + lane * 8);
            acc[0][0] = __builtin_amdgcn_mfma_f32_32x32x16_bf16(a0, b0, acc[0][0], 0, 0, 0);
            acc[0][1] = __builtin_amdgcn_mfma_f32_32x32x16_bf16(a0, b1, acc[0][1], 0, 0, 0);
            acc[1][0] = __builtin_amdgcn_mfma_f32_32x32x16_bf16(a1, b0, acc[1][0], 0, 0, 0);
            acc[1][1] = __builtin_amdgcn_mfma_f32_32x32x16_bf16(a1, b1, acc[1][1], 0, 0, 0);
        }
    }

    // epilogue: relu + BN, D layout col=lane&31, row=(r&3)+8*(r>>2)+4*kg
    const int x_out = 2 * BX + w;
#pragma unroll
    for (int nt = 0; nt < 2; ++nt) {
        int co = nt * 32 + lz;
        float scale = g[co] * rsqrtf(v[co] + EPSB);
        float shift = be[co] - m[co] * scale;
        float bias = cb[co];
#pragma unroll
        for (int mt = 0; mt < 2; ++mt) {
            int y_out = 2 * BY + mt;
            size_t base = (size_t)((x_out * DIMV) + y_out) * DIMV * CH + co;
#pragma unroll
            for (int r = 0; r < 16; ++r) {
                int zrow = (r & 3) + 8 * (r >> 2) + 4 * kg;
                int z = BZ * 32 + zrow;
                float val = fmaxf(acc[mt][nt][r] + bias, 0.f) * scale + shift;
                store_out(&out[base + (size_t)z * CH], val);
            }
        }
    }
}

// ---------------- trilinear gather (fp32 grid) ----------------
__global__ void gather_kernel(const float* __restrict__ grid, const float* __restrict__ pts,
                              float* __restrict__ out, int n_total) {
    int tid = blockIdx.x * blockDim.x + threadIdx.x;
    if (tid >= n_total) return;
    int n = tid >> 6, c = tid & 63;
    float px = fminf(fmaxf(pts[n * 3 + 0], 0.f), (float)(DIMV - 1));
    float py = fminf(fmaxf(pts[n * 3 + 1], 0.f), (float)(DIMV - 1));
    float pz = fminf(fmaxf(pts[n * 3 + 2], 0.f), (float)(DIMV - 1));
    float fx = floorf(px), fy = floorf(py), fz = floorf(pz);
    float tx = px - fx, ty = py - fy, tz = pz - fz;
    int x0 = (int)fx, y0 = (int)fy, z0 = (int)fz;
    int x1 = min(x0 + 1, DIMV - 1), y1 = min(y0 + 1, DIMV - 1), z1 = min(z0 + 1, DIMV - 1);
    float wx0 = 1.f - tx, wy0 = 1.f - ty, wz0 = 1.f - tz;

    float acc = 0.f;
    acc = fmaf(wx0 * wy0 * wz0, grid[(size_t)(((x0 * DIMV) + y0) * DIMV + z0) * CH + c], acc);
    acc = fmaf(wx0 * wy0 * tz,  grid[(size_t)(((x0 * DIMV) + y0) * DIMV + z1) * CH + c], acc);
    acc = fmaf(wx0 * ty * wz0,  grid[(size_t)(((x0 * DIMV) + y1) * DIMV + z0) * CH + c], acc);
    acc = fmaf(wx0 * ty * tz,   grid[(size_t)(((x0 * DIMV) + y1) * DIMV + z1) * CH + c], acc);
    acc = fmaf(tx * wy0 * wz0,  grid[(size_t)(((x1 * DIMV) + y0) * DIMV + z0) * CH + c], acc);
    acc = fmaf(tx * wy0 * tz,   grid[(size_t)(((x1 * DIMV) + y0) * DIMV + z1) * CH + c], acc);
    acc = fmaf(tx * ty * wz0,   grid[(size_t)(((x1 * DIMV) + y1) * DIMV + z0) * CH + c], acc);
    acc = fmaf(tx * ty * tz,    grid[(size_t)(((x1 * DIMV) + y1) * DIMV + z1) * CH + c], acc);
    out[tid] += acc;
}

extern "C" void kernel_launch(void* const* d_in, const int* in_sizes, int n_in,
                              void* d_out, int out_size, void* d_ws, size_t ws_size,
                              hipStream_t stream) {
    const float* inputs = (const float*)d_in[0];
    const float* pt_coords = (const float*)d_in[1];
    const int* voxel_indexes = (const int*)d_in[2];
    const float* ppvi = (const float*)d_in[3];
    const float* w_mlp = (const float*)d_in[4];
    const float* b_mlp = (const float*)d_in[5];
    const float* g0 = (const float*)d_in[6];
    const float* be0 = (const float*)d_in[7];
    const float* m0 = (const float*)d_in[8];
    const float* v0 = (const float*)d_in[9];
    const float* k1 = (const float*)d_in[10];
    const float* cb1 = (const float*)d_in[11];
    const float* g1 = (const float*)d_in[12];
    const float* be1 = (const float*)d_in[13];
    const float* m1 = (const float*)d_in[14];
    const float* v1 = (const float*)d_in[15];
    const float* k2 = (const float*)d_in[16];
    const float* cb2 = (const float*)d_in[17];
    const float* g2 = (const float*)d_in[18];
    const float* be2 = (const float*)d_in[19];
    const float* m2 = (const float*)d_in[20];
    const float* v2 = (const float*)d_in[21];
    float* out = (float*)d_out;

    char* ws = (char*)d_ws;
    // [0,67.1M): A fp32 grid (scatter), later reused: G2 bf16 [0,33.5M) + wbufs
    // [67.1M,100.7M): G1 bf16 (pack out); later overwritten by G3 fp32 [67.1M,134.2M)
    float* A = (float*)ws;
    unsigned short* G2 = (unsigned short*)ws;
    unsigned short* wbuf1 = (unsigned short*)(ws + 33554432);
    unsigned short* wbuf2 = (unsigned short*)(ws + 33775616);
    unsigned short* G1 = (unsigned short*)(ws + 67108864);
    float* G3 = (float*)(ws + 67108864);

    const int n_total = in_sizes[0];           // N * C
    const int nblk = (n_total + 255) / 256;
    const size_t grid_elems = (size_t)DIMV * DIMV * DIMV * CH;

    hipMemsetAsync(A, 0, grid_elems * sizeof(float), stream);
    mlp_kernel<<<nblk, 256, 0, stream>>>(inputs, w_mlp, b_mlp, g0, be0, m0, v0, out, n_total);
    scatter_kernel<<<nblk, 256, 0, stream>>>(inputs, voxel_indexes, A, n_total);
    pack_kernel<<<(int)(grid_elems / 8 + 255) / 256, 256, 0, stream>>>(A, ppvi, G1);
    wprep_kernel<<<432, 256, 0, stream>>>(k1, wbuf1);
    wprep_kernel<<<432, 256, 0, stream>>>(k2, wbuf2);

    dim3 cgrid(32, 32, 2);
    conv_mfma<unsigned short><<<cgrid, 128, 0, stream>>>(G1, wbuf1, cb1, g1, be1, m1, v1, G2);
    conv_mfma<float><<<cgrid, 128, 0, stream>>>(G2, wbuf2, cb2, g2, be2, m2, v2, G3);

    gather_kernel<<<nblk, 256, 0, stream>>>(G3, pt_coords, out, n_total);
}

// Round 3
// 376.391 us; speedup vs baseline: 7.7317x; 1.4578x over previous
//
#include <hip/hip_runtime.h>
#include <hip/hip_bf16.h>

#define DIMV 64
#define CH 64
#define EPSB 1e-3f

using bf16x8 = __attribute__((ext_vector_type(8))) short;
using f32x16 = __attribute__((ext_vector_type(16))) float;

__device__ __forceinline__ unsigned short f2bf(float f) {
    union { float f; unsigned u; } x; x.f = f;
    unsigned r = x.u + 0x7fff + ((x.u >> 16) & 1);   // round-to-nearest-even
    return (unsigned short)(r >> 16);
}
__device__ __forceinline__ float bf2f(unsigned short u) {
    union { unsigned u; float f; } x; x.u = ((unsigned)u) << 16;
    return x.f;
}

__device__ __forceinline__ void store_out(unsigned short* p, float v) { *p = f2bf(v); }
__device__ __forceinline__ void store_out(float* p, float v) { *p = v; }

// ---------------- point branch: MFMA GEMM [N,64]x[64,64] + relu + BN ----------------
__global__ __launch_bounds__(256) void mlp_mfma(
    const float* __restrict__ x, const float* __restrict__ W,
    const float* __restrict__ b, const float* __restrict__ g,
    const float* __restrict__ be, const float* __restrict__ m,
    const float* __restrict__ v, float* __restrict__ out, int npts) {
    const int wid = blockIdx.x * 4 + (threadIdx.x >> 6);
    if (wid * 32 >= npts) return;
    const int lane = threadIdx.x & 63;
    const int col = lane & 31;       // A-row / B-col / C-col
    const int kg = lane >> 5;        // k-half within 16-step
    const int p0 = wid * 32;

    // A fragments: row = col (point p0+col), k = kk*16 + kg*8 + j
    bf16x8 a[4];
    const float* xr = x + (size_t)(p0 + col) * CH + kg * 8;
#pragma unroll
    for (int kk = 0; kk < 4; ++kk) {
        const float* p = xr + kk * 16;
        bf16x8 t;
#pragma unroll
        for (int j = 0; j < 8; ++j) t[j] = (short)f2bf(p[j]);
        a[kk] = t;
    }

    // B fragments: B[k][co], k = kk*16 + kg*8 + j, co = nt*32 + col
    bf16x8 bb[4][2];
#pragma unroll
    for (int kk = 0; kk < 4; ++kk)
#pragma unroll
        for (int nt = 0; nt < 2; ++nt) {
            bf16x8 t;
#pragma unroll
            for (int j = 0; j < 8; ++j)
                t[j] = (short)f2bf(W[(size_t)(kk * 16 + kg * 8 + j) * CH + nt * 32 + col]);
            bb[kk][nt] = t;
        }

    f32x16 acc[2];
#pragma unroll
    for (int nt = 0; nt < 2; ++nt)
#pragma unroll
        for (int r = 0; r < 16; ++r) acc[nt][r] = 0.f;

#pragma unroll
    for (int kk = 0; kk < 4; ++kk) {
        acc[0] = __builtin_amdgcn_mfma_f32_32x32x16_bf16(a[kk], bb[kk][0], acc[0], 0, 0, 0);
        acc[1] = __builtin_amdgcn_mfma_f32_32x32x16_bf16(a[kk], bb[kk][1], acc[1], 0, 0, 0);
    }

    // D layout: col = lane&31, row = (r&3) + 8*(r>>2) + 4*kg
#pragma unroll
    for (int nt = 0; nt < 2; ++nt) {
        int co = nt * 32 + col;
        float scale = g[co] * rsqrtf(v[co] + EPSB);
        float shift = be[co] - m[co] * scale;
        float bias = b[co];
#pragma unroll
        for (int r = 0; r < 16; ++r) {
            int row = (r & 3) + 8 * (r >> 2) + 4 * kg;
            float val = fmaxf(acc[nt][r] + bias, 0.f) * scale + shift;
            out[(size_t)(p0 + row) * CH + co] = val;
        }
    }
}

__global__ void scatter_kernel(const float* __restrict__ x, const int* __restrict__ idx,
                               float* __restrict__ grid, int n_total) {
    int tid = blockIdx.x * blockDim.x + threadIdx.x;
    if (tid >= n_total) return;
    int n = tid >> 6, c = tid & 63;
    int ix = idx[n * 3 + 0], iy = idx[n * 3 + 1], iz = idx[n * 3 + 2];
    atomicAdd(&grid[(size_t)(((ix * DIMV) + iy) * DIMV + iz) * CH + c], x[tid]);
}

// ---------------- pack: fp32 grid * inv -> bf16 grid ----------------
__global__ void pack_kernel(const float* __restrict__ A, const float* __restrict__ inv,
                            unsigned short* __restrict__ G1) {
    int t = blockIdx.x * 256 + threadIdx.x;          // one 16B chunk (8 ch) per thread
    if (t >= (DIMV * DIMV * DIMV * CH) / 8) return;
    int v = t >> 3, c8 = (t & 7) * 8;
    const float* src = A + (size_t)v * CH + c8;
    float s = inv[v];
    __align__(16) unsigned short tmp[8];
#pragma unroll
    for (int j = 0; j < 8; ++j) tmp[j] = f2bf(src[j] * s);
    *(int4*)(G1 + (size_t)t * 8) = *(const int4*)tmp;
}

// ---------------- weight repack into MFMA B-fragment layout ----------------
__global__ void wprep_kernel(const float* __restrict__ K, unsigned short* __restrict__ wbuf) {
    int t = blockIdx.x * 256 + threadIdx.x;
    if (t >= 27 * 4 * 2 * 64 * 8) return;
    int j = t & 7;
    int l = (t >> 3) & 63;
    int nt = (t >> 9) & 1;
    int kkl = (t >> 10) & 3;
    int d = t >> 12;
    int ci = kkl * 16 + (l >> 5) * 8 + j;
    int co = nt * 32 + (l & 31);
    wbuf[t] = f2bf(K[((size_t)d * 64 + ci) * 64 + co]);
}

// ---------------- MFMA conv: C-tile 128x64 per block (2x2 xy cols x 32 z) ----------------
template <typename OutT>
__global__ __launch_bounds__(128) void conv_mfma(
    const unsigned short* __restrict__ G, const unsigned short* __restrict__ wbuf,
    const float* __restrict__ cb, const float* __restrict__ g,
    const float* __restrict__ be, const float* __restrict__ m,
    const float* __restrict__ v, OutT* __restrict__ out) {
    __shared__ __align__(16) unsigned short slab[4 * 4 * 34 * 64];  // 69632 B, swizzled
    __shared__ __align__(16) unsigned short bsm[4096];              // 8192 B
    const int tid = threadIdx.x;
    const int lane = tid & 63;
    const int w = tid >> 6;         // wave 0/1 -> x column
    const int lz = lane & 31;
    const int kg = lane >> 5;       // k-half
    const int BX = blockIdx.x, BY = blockIdx.y, BZ = blockIdx.z;
    const int x0 = 2 * BX - 1, y0 = 2 * BY - 1, z0 = 32 * BZ - 1;

    for (int it = 0; it < 34; ++it) {
        int idx = it * 128 + tid;
        int s = idx & 7;
        int r = idx >> 3;
        int zloc = r % 34;
        int ryx = r / 34;
        int yy = y0 + (ryx & 3);
        int xx = x0 + (ryx >> 2);
        int zz = z0 + zloc;
        int cg = s ^ (zloc & 7);
        int4 val = make_int4(0, 0, 0, 0);
        if ((unsigned)xx < DIMV && (unsigned)yy < DIMV && (unsigned)zz < DIMV)
            val = *(const int4*)(G + ((size_t)(((xx * DIMV) + yy) * DIMV + zz) * CH + cg * 8));
        *(int4*)(slab + r * 64 + s * 8) = val;
    }

    f32x16 acc[2][2];
#pragma unroll
    for (int mt = 0; mt < 2; ++mt)
#pragma unroll
        for (int nt = 0; nt < 2; ++nt)
#pragma unroll
            for (int r = 0; r < 16; ++r) acc[mt][nt][r] = 0.f;

    for (int d = 0; d < 27; ++d) {
        __syncthreads();
        const int4* wsrc = (const int4*)(wbuf + (size_t)d * 4096);
#pragma unroll
        for (int i = 0; i < 4; ++i) ((int4*)bsm)[i * 128 + tid] = wsrc[i * 128 + tid];
        __syncthreads();

        const int dx = d / 9, dy = (d / 3) % 3, dz = d % 3;
        const int zloc = lz + dz;
        const int swz = zloc & 7;
        const int rb0 = (((w + dx) * 4 + dy) * 34 + zloc) * 64;

#pragma unroll
        for (int kkl = 0; kkl < 4; ++kkl) {
            const int coff = ((kkl * 2 + kg) ^ swz) * 8;
            bf16x8 a0 = *(const bf16x8*)(slab + rb0 + coff);
            bf16x8 a1 = *(const bf16x8*)(slab + rb0 + 34 * 64 + coff);
            bf16x8 b0 = *(const bf16x8*)(bsm + kkl * 1024 + lane * 8);
            bf16x8 b1 = *(const bf16x8*)(bsm + kkl * 1024 + 512 + lane * 8);
            acc[0][0] = __builtin_amdgcn_mfma_f32_32x32x16_bf16(a0, b0, acc[0][0], 0, 0, 0);
            acc[0][1] = __builtin_amdgcn_mfma_f32_32x32x16_bf16(a0, b1, acc[0][1], 0, 0, 0);
            acc[1][0] = __builtin_amdgcn_mfma_f32_32x32x16_bf16(a1, b0, acc[1][0], 0, 0, 0);
            acc[1][1] = __builtin_amdgcn_mfma_f32_32x32x16_bf16(a1, b1, acc[1][1], 0, 0, 0);
        }
    }

    const int x_out = 2 * BX + w;
#pragma unroll
    for (int nt = 0; nt < 2; ++nt) {
        int co = nt * 32 + lz;
        float scale = g[co] * rsqrtf(v[co] + EPSB);
        float shift = be[co] - m[co] * scale;
        float bias = cb[co];
#pragma unroll
        for (int mt = 0; mt < 2; ++mt) {
            int y_out = 2 * BY + mt;
            size_t base = (size_t)((x_out * DIMV) + y_out) * DIMV * CH + co;
#pragma unroll
            for (int r = 0; r < 16; ++r) {
                int zrow = (r & 3) + 8 * (r >> 2) + 4 * kg;
                int z = BZ * 32 + zrow;
                float val = fmaxf(acc[mt][nt][r] + bias, 0.f) * scale + shift;
                store_out(&out[base + (size_t)z * CH], val);
            }
        }
    }
}

// ---------------- trilinear gather (bf16 grid) ----------------
__global__ void gather_kernel(const unsigned short* __restrict__ grid,
                              const float* __restrict__ pts,
                              float* __restrict__ out, int n_total) {
    int tid = blockIdx.x * blockDim.x + threadIdx.x;
    if (tid >= n_total) return;
    int n = tid >> 6, c = tid & 63;
    float px = fminf(fmaxf(pts[n * 3 + 0], 0.f), (float)(DIMV - 1));
    float py = fminf(fmaxf(pts[n * 3 + 1], 0.f), (float)(DIMV - 1));
    float pz = fminf(fmaxf(pts[n * 3 + 2], 0.f), (float)(DIMV - 1));
    float fx = floorf(px), fy = floorf(py), fz = floorf(pz);
    float tx = px - fx, ty = py - fy, tz = pz - fz;
    int x0 = (int)fx, y0 = (int)fy, z0 = (int)fz;
    int x1 = min(x0 + 1, DIMV - 1), y1 = min(y0 + 1, DIMV - 1), z1 = min(z0 + 1, DIMV - 1);
    float wx0 = 1.f - tx, wy0 = 1.f - ty, wz0 = 1.f - tz;

    float acc = 0.f;
    acc = fmaf(wx0 * wy0 * wz0, bf2f(grid[(size_t)(((x0 * DIMV) + y0) * DIMV + z0) * CH + c]), acc);
    acc = fmaf(wx0 * wy0 * tz,  bf2f(grid[(size_t)(((x0 * DIMV) + y0) * DIMV + z1) * CH + c]), acc);
    acc = fmaf(wx0 * ty * wz0,  bf2f(grid[(size_t)(((x0 * DIMV) + y1) * DIMV + z0) * CH + c]), acc);
    acc = fmaf(wx0 * ty * tz,   bf2f(grid[(size_t)(((x0 * DIMV) + y1) * DIMV + z1) * CH + c]), acc);
    acc = fmaf(tx * wy0 * wz0,  bf2f(grid[(size_t)(((x1 * DIMV) + y0) * DIMV + z0) * CH + c]), acc);
    acc = fmaf(tx * wy0 * tz,   bf2f(grid[(size_t)(((x1 * DIMV) + y0) * DIMV + z1) * CH + c]), acc);
    acc = fmaf(tx * ty * wz0,   bf2f(grid[(size_t)(((x1 * DIMV) + y1) * DIMV + z0) * CH + c]), acc);
    acc = fmaf(tx * ty * tz,    bf2f(grid[(size_t)(((x1 * DIMV) + y1) * DIMV + z1) * CH + c]), acc);
    out[tid] += acc;
}

extern "C" void kernel_launch(void* const* d_in, const int* in_sizes, int n_in,
                              void* d_out, int out_size, void* d_ws, size_t ws_size,
                              hipStream_t stream) {
    const float* inputs = (const float*)d_in[0];
    const float* pt_coords = (const float*)d_in[1];
    const int* voxel_indexes = (const int*)d_in[2];
    const float* ppvi = (const float*)d_in[3];
    const float* w_mlp = (const float*)d_in[4];
    const float* b_mlp = (const float*)d_in[5];
    const float* g0 = (const float*)d_in[6];
    const float* be0 = (const float*)d_in[7];
    const float* m0 = (const float*)d_in[8];
    const float* v0 = (const float*)d_in[9];
    const float* k1 = (const float*)d_in[10];
    const float* cb1 = (const float*)d_in[11];
    const float* g1 = (const float*)d_in[12];
    const float* be1 = (const float*)d_in[13];
    const float* m1 = (const float*)d_in[14];
    const float* v1 = (const float*)d_in[15];
    const float* k2 = (const float*)d_in[16];
    const float* cb2 = (const float*)d_in[17];
    const float* g2 = (const float*)d_in[18];
    const float* be2 = (const float*)d_in[19];
    const float* m2 = (const float*)d_in[20];
    const float* v2 = (const float*)d_in[21];
    float* out = (float*)d_out;

    char* ws = (char*)d_ws;
    // Layout (bytes):
    // [0, 67.1M):    A fp32 scatter grid; later reused: G2 bf16 [0,33.5M), G3 bf16 [33.5M,67.1M)
    // [67.1M,100.7M): G1 bf16 (pack output, conv1 input)
    // [100.7M, +):   wbuf1, wbuf2 (221184 B each)
    float* A = (float*)ws;
    unsigned short* G2 = (unsigned short*)ws;
    unsigned short* G3 = (unsigned short*)(ws + 33554432);
    unsigned short* G1 = (unsigned short*)(ws + 67108864);
    unsigned short* wbuf1 = (unsigned short*)(ws + 100663296);
    unsigned short* wbuf2 = (unsigned short*)(ws + 100884480);

    const int n_total = in_sizes[0];           // N * C
    const int npts = n_total / CH;
    const int nblk = (n_total + 255) / 256;
    const size_t grid_elems = (size_t)DIMV * DIMV * DIMV * CH;

    hipMemsetAsync(A, 0, grid_elems * sizeof(float), stream);
    mlp_mfma<<<(npts / 32 + 3) / 4, 256, 0, stream>>>(inputs, w_mlp, b_mlp, g0, be0, m0, v0, out, npts);
    scatter_kernel<<<nblk, 256, 0, stream>>>(inputs, voxel_indexes, A, n_total);
    pack_kernel<<<(int)(grid_elems / 8 + 255) / 256, 256, 0, stream>>>(A, ppvi, G1);
    wprep_kernel<<<432, 256, 0, stream>>>(k1, wbuf1);
    wprep_kernel<<<432, 256, 0, stream>>>(k2, wbuf2);

    dim3 cgrid(32, 32, 2);
    conv_mfma<unsigned short><<<cgrid, 128, 0, stream>>>(G1, wbuf1, cb1, g1, be1, m1, v1, G2);
    conv_mfma<unsigned short><<<cgrid, 128, 0, stream>>>(G2, wbuf2, cb2, g2, be2, m2, v2, G3);

    gather_kernel<<<nblk, 256, 0, stream>>>(G3, pt_coords, out, n_total);
}